// Round 10
// baseline (761.686 us; speedup 1.0000x reference)
//
#include <hip/hip_runtime.h>
#include <hip/hip_fp16.h>

#define FEAT 128
#define BSH 8              // 256 nodes per bucket
#define BSZ 256
#define NBMAX 400
#define ABLK 4096          // edges per pass-A block
#define CAP 6144           // tmp region capacity per bucket (mean 4092, >30 sigma)

typedef _Float16 half_t;
typedef _Float16 half4 __attribute__((ext_vector_type(4)));
typedef _Float16 half8 __attribute__((ext_vector_type(8)));
typedef float float4v __attribute__((ext_vector_type(4)));

// ---------------- bucket cursor init: fixed regions ----------------
__global__ void binit_kernel(int* __restrict__ gcur, int NB) {
    int b = blockIdx.x * blockDim.x + threadIdx.x;
    if (b < NB) gcur[b * 16] = b * CAP;
}

// ---------------- pass A: LDS-aggregated bucket scatter of raw {r,c} ----------------
__global__ __launch_bounds__(256) void bucketA_kernel(const int* __restrict__ row,
                                                      const int* __restrict__ col,
                                                      int* __restrict__ gcur,
                                                      long long* __restrict__ tmp,
                                                      int E, int NB) {
    __shared__ int hist[NBMAX];
    __shared__ int gbase[NBMAX];
    int t = threadIdx.x;
    int base = blockIdx.x * ABLK;
    for (int i = t; i < NB; i += 256) hist[i] = 0;
    __syncthreads();
    int r[16], c[16];
#pragma unroll
    for (int j = 0; j < 16; ++j) {
        int e = base + j * 256 + t;
        if (e < E) {
            r[j] = __builtin_nontemporal_load(row + e);
            c[j] = __builtin_nontemporal_load(col + e);
            atomicAdd(&hist[c[j] >> BSH], 1);
        } else c[j] = -1;
    }
    __syncthreads();
    for (int b = t; b < NB; b += 256) {
        int cnt = hist[b];
        if (cnt > 0) gbase[b] = atomicAdd(&gcur[b * 16], cnt);
    }
    __syncthreads();
    for (int i = t; i < NB; i += 256) hist[i] = 0;   // reuse as local cursor
    __syncthreads();
#pragma unroll
    for (int j = 0; j < 16; ++j) {
        if (c[j] >= 0) {
            int b = c[j] >> BSH;
            int lpos = atomicAdd(&hist[b], 1);
            long long pk = ((long long)(unsigned)c[j] << 32) | (unsigned)r[j];
            tmp[gbase[b] + lpos] = pk;
        }
    }
}

// ---------------- bucket-count scan ----------------
__global__ __launch_bounds__(512) void bscan_kernel(const int* __restrict__ gcur,
                                                    int* __restrict__ bbase,
                                                    int* __restrict__ offsN, int NB) {
    __shared__ int sd[512];
    int t = threadIdx.x;
    int v = (t < NB) ? (gcur[t * 16] - t * CAP) : 0;
    sd[t] = v;
    __syncthreads();
    for (int o = 1; o < 512; o <<= 1) {
        int u = (t >= o) ? sd[t - o] : 0;
        __syncthreads();
        sd[t] += u;
        __syncthreads();
    }
    if (t < NB) bbase[t] = sd[t] - v;    // exclusive
    if (t == NB - 1) *offsN = sd[t];     // offs[N] = E
}

// ---------------- bdeg: per-bucket degree count (LDS atomics) + offs + dinv ----------------
__global__ __launch_bounds__(256) void bdeg_kernel(const long long* __restrict__ tmp,
                                                   const int* __restrict__ gcur,
                                                   const int* __restrict__ bbase,
                                                   int* __restrict__ offs,
                                                   float* __restrict__ dinv, int N) {
    __shared__ int ldeg[BSZ];
    __shared__ int sums[BSZ];
    int b = blockIdx.x;
    int lo = b << BSH;
    int t = threadIdx.x;
    int cnt = gcur[b * 16] - b * CAP;
    ldeg[t] = 0;
    __syncthreads();
    const long long* reg = tmp + (size_t)b * CAP;
    for (int i = t; i < cnt; i += 256) {
        int c = (int)(__builtin_nontemporal_load(reg + i) >> 32);
        atomicAdd(&ldeg[c - lo], 1);
    }
    __syncthreads();
    int d = ldeg[t];
    sums[t] = d;
    __syncthreads();
    for (int o = 1; o < 256; o <<= 1) {
        int u = (t >= o) ? sums[t - o] : 0;
        __syncthreads();
        sums[t] += u;
        __syncthreads();
    }
    int node = lo + t;
    if (node < N) {
        offs[node] = bbase[b] + sums[t] - d;
        dinv[node] = (d > 0) ? rsqrtf((float)d) : 0.0f;
    }
}

// ---------------- bplace: per-bucket CSR fill with LDS cursors ----------------
__global__ __launch_bounds__(256) void bplace_kernel(const long long* __restrict__ tmp,
                                                     const int* __restrict__ gcur,
                                                     const int* __restrict__ offs,
                                                     const float* __restrict__ dinv,
                                                     int2* __restrict__ csr, int N) {
    __shared__ int lcur[BSZ];
    int b = blockIdx.x;
    int lo = b << BSH;
    int hi = lo + BSZ;
    if (hi > N) hi = N;
    int t = threadIdx.x;
    int cnt = gcur[b * 16] - b * CAP;
    if (t < hi - lo) lcur[t] = offs[lo + t];
    __syncthreads();
    const long long* reg = tmp + (size_t)b * CAP;
    for (int i = t; i < cnt; i += 256) {
        long long pk = __builtin_nontemporal_load(reg + i);
        int r = (int)(pk & 0xffffffffLL);
        int c = (int)(pk >> 32);
        int pos = atomicAdd(&lcur[c - lo], 1);
        float w = dinv[r] * dinv[c];
        int2 o;
        o.x = r;
        o.y = __float_as_int(w);
        csr[pos] = o;
    }
}

// ---------------- fused fp32->fp16 convert for x, W1, W2 ----------------
__global__ void f2h3_kernel(const float* __restrict__ a, half_t* __restrict__ ah, int na4,
                            const float* __restrict__ b, half_t* __restrict__ bh, int nb4,
                            const float* __restrict__ c, half_t* __restrict__ ch, int nc4) {
    int i = blockIdx.x * blockDim.x + threadIdx.x;
    const float* src;
    half_t* dst;
    int j = i;
    if (j < na4) { src = a; dst = ah; }
    else if ((j -= na4) < nb4) { src = b; dst = bh; }
    else if ((j -= nb4) < nc4) { src = c; dst = ch; }
    else return;
    float4 v = ((const float4*)src)[j];
    half4 o;
    o.x = (half_t)v.x; o.y = (half_t)v.y; o.z = (half_t)v.z; o.w = (half_t)v.w;
    ((half4*)dst)[j] = o;
}

// ---------------- fp16 propagation hop, HALF-FEATURE pass ----------------
// One 64-lane wave per node, features [d0, d0+64). Lane = (slot q=lane>>3, chunk p=lane&7):
// one wave instruction gathers 8 half-rows of 128B (16 lines). Sequential passes shrink
// the concurrent src working set to 12.8MB -> better L2 hit rate.
__global__ __launch_bounds__(256) void prop16_kernel(const half_t* __restrict__ src,
                                                     half_t* __restrict__ dst,
                                                     const int* __restrict__ offs,
                                                     const long long* __restrict__ csr,
                                                     int N, int d0) {
    int v = blockIdx.x * 4 + (threadIdx.x >> 6);
    if (v >= N) return;
    int lane = threadIdx.x & 63;
    int q = lane >> 3;     // edge slot 0..7
    int p = lane & 7;      // 16B chunk within 128B half-row
    int s0 = offs[v];
    int s1 = offs[v + 1];
    float acc[8];
#pragma unroll
    for (int j = 0; j < 8; ++j) acc[j] = 0.0f;

    for (int base = s0; base < s1; base += 8) {
        int i0 = base + q;
        long long pk0 = (i0 < s1) ? __builtin_nontemporal_load(csr + i0) : 0LL;
        int r0 = (int)(pk0 & 0xffffffffLL);
        float w0 = __int_as_float((int)(pk0 >> 32));
        half8 va = *(const half8*)(src + (size_t)r0 * FEAT + d0 + p * 8);
#pragma unroll
        for (int j = 0; j < 8; ++j) {
            acc[j] = fmaf(w0, (float)va[j], acc[j]);
        }
    }
    // sum the 8 edge slots (lanes p, p+8, ..., p+56 hold the same features)
#pragma unroll
    for (int j = 0; j < 8; ++j) {
        acc[j] += __shfl_xor(acc[j], 32, 64);
        acc[j] += __shfl_xor(acc[j], 16, 64);
        acc[j] += __shfl_xor(acc[j], 8, 64);
    }
    if (lane < 8) {
        half8 o;
#pragma unroll
        for (int j = 0; j < 8; ++j) o[j] = (half_t)acc[j];
        *(half8*)(dst + (size_t)v * FEAT + d0 + p * 8) = o;
    }
}

// ---------------- MFMA GEMM: out[M,128] = concat(H0..H3)[M,512] @ W[128,512].T + b ----------------
template <bool RELU, bool HALFOUT>
__global__ __launch_bounds__(256) void gemm16_kernel(const half_t* __restrict__ H0,
                                                     const half_t* __restrict__ H1,
                                                     const half_t* __restrict__ H2,
                                                     const half_t* __restrict__ H3,
                                                     const half_t* __restrict__ W,   // [128][512] fp16
                                                     const float* __restrict__ bias, // [128] fp32
                                                     half_t* __restrict__ out_h,
                                                     float* __restrict__ out_f, int N) {
    __shared__ half_t ws[128][40];   // [o][k-slice 32, pad->40]
    const int tid = threadIdx.x;
    const int lane = tid & 63;
    const int wid = tid >> 6;
    const int lr = lane & 15;        // m-in-tile
    const int lk = lane >> 4;        // 0..3
    const int m = blockIdx.x * 64 + wid * 16 + lr;
    const bool mok = (m < N);

    float4v acc[8];
#pragma unroll
    for (int ct = 0; ct < 8; ++ct) acc[ct] = (float4v)0.0f;

    const half_t* Hs[4] = {H0, H1, H2, H3};
    const int wo = tid >> 1;
    const int wh = tid & 1;

#pragma unroll
    for (int b = 0; b < 4; ++b) {
        const half_t* __restrict__ H = Hs[b];
#pragma unroll
        for (int kt = 0; kt < 128; kt += 32) {
            half8 hfrag = (half8)(half_t)0.0f;
            if (mok) hfrag = *(const half8*)(H + (size_t)m * FEAT + kt + lk * 8);
            const half8* wsrc = (const half8*)(W + (size_t)wo * 512 + b * 128 + kt + wh * 16);
            half8 w0 = wsrc[0];
            half8 w1 = wsrc[1];
            __syncthreads();
            *(half8*)&ws[wo][wh * 16 + 0] = w0;
            *(half8*)&ws[wo][wh * 16 + 8] = w1;
            __syncthreads();
#pragma unroll
            for (int ct = 0; ct < 8; ++ct) {
                half8 wfrag = *(const half8*)&ws[ct * 16 + lr][lk * 8];
                acc[ct] = __builtin_amdgcn_mfma_f32_16x16x32_f16(wfrag, hfrag, acc[ct], 0, 0, 0);
            }
        }
    }

    if (mok) {
#pragma unroll
        for (int ct = 0; ct < 8; ++ct) {
            int o = ct * 16 + lk * 4;
            float4 bv = *(const float4*)(bias + o);
            float r0 = acc[ct][0] + bv.x;
            float r1 = acc[ct][1] + bv.y;
            float r2 = acc[ct][2] + bv.z;
            float r3 = acc[ct][3] + bv.w;
            if (RELU) {
                r0 = fmaxf(r0, 0.0f); r1 = fmaxf(r1, 0.0f);
                r2 = fmaxf(r2, 0.0f); r3 = fmaxf(r3, 0.0f);
            }
            if (HALFOUT) {
                half4 hv;
                hv.x = (half_t)r0; hv.y = (half_t)r1; hv.z = (half_t)r2; hv.w = (half_t)r3;
                *(half4*)(out_h + (size_t)m * FEAT + o) = hv;
            } else {
                float4 fv;
                fv.x = r0; fv.y = r1; fv.z = r2; fv.w = r3;
                *(float4*)(out_f + (size_t)m * FEAT + o) = fv;
            }
        }
    }
}

extern "C" void kernel_launch(void* const* d_in, const int* in_sizes, int n_in,
                              void* d_out, int out_size, void* d_ws, size_t ws_size,
                              hipStream_t stream) {
    const float* x   = (const float*)d_in[0];
    const int*   ei  = (const int*)d_in[1];
    const float* W1  = (const float*)d_in[2];
    const float* b1  = (const float*)d_in[3];
    const float* W2  = (const float*)d_in[4];
    const float* b2  = (const float*)d_in[5];
    float* out = (float*)d_out;

    const int N = in_sizes[0] / FEAT;       // 100000
    const int E = in_sizes[1] / 2;          // 1600000
    const int* row = ei;
    const int* col = ei + E;
    const int NB = (N + BSZ - 1) / BSZ;     // buckets (391)

    // workspace carve
    size_t off = 0;
    auto carve = [&](size_t bytes) -> void* {
        void* p = (char*)d_ws + off;
        off += (bytes + 255) & ~(size_t)255;
        return p;
    };
    float*     dinv = (float*)carve((size_t)N * 4);
    int*       offs = (int*)carve((size_t)(N + 1) * 4);
    int*       bbase = (int*)carve((size_t)NB * 4);
    int*       gcur = (int*)carve((size_t)NB * 16 * 4);   // padded cursors
    long long* tmp  = (long long*)carve((size_t)NB * CAP * 8);
    int2*      csr  = (int2*)carve((size_t)E * 8);
    half_t*    x16  = (half_t*)carve((size_t)N * FEAT * 2);
    half_t*    t1   = (half_t*)carve((size_t)N * FEAT * 2);
    half_t*    t2   = (half_t*)carve((size_t)N * FEAT * 2);
    half_t*    t3   = (half_t*)carve((size_t)N * FEAT * 2);
    half_t*    hbuf = (half_t*)carve((size_t)N * FEAT * 2);
    half_t*    w1h  = (half_t*)carve((size_t)FEAT * 512 * 2);
    half_t*    w2h  = (half_t*)carve((size_t)FEAT * 512 * 2);

    const int tB = 256;
    const int gA = (E + ABLK - 1) / ABLK;       // pass-A blocks
    const int gP = (N + 3) / 4;                 // prop16 blocks (4 nodes/block, 1 wave/node)
    const int gG = (N + 63) / 64;               // gemm16 blocks (64 rows/block)
    const int xt4 = N * FEAT / 4;
    const int wt4 = FEAT * 512 / 4;
    const int cvt_total = xt4 + 2 * wt4;

    // ---- CSR build: bucket scatter -> bucket scan -> LDS degree count -> place ----
    binit_kernel<<<(NB + tB - 1) / tB, tB, 0, stream>>>(gcur, NB);
    bucketA_kernel<<<gA, 256, 0, stream>>>(row, col, gcur, tmp, E, NB);
    bscan_kernel<<<1, 512, 0, stream>>>(gcur, bbase, offs + N, NB);
    bdeg_kernel<<<NB, 256, 0, stream>>>(tmp, gcur, bbase, offs, dinv, N);
    bplace_kernel<<<NB, 256, 0, stream>>>(tmp, gcur, offs, dinv, csr, N);

    // ---- fp16 conversions (fused) ----
    f2h3_kernel<<<(cvt_total + tB - 1) / tB, tB, 0, stream>>>(x, x16, xt4, W1, w1h, wt4, W2, w2h, wt4);

    const long long* csrll = (const long long*)csr;

    // two half-feature passes per hop (shrinks concurrent src working set)
    auto prop = [&](const half_t* s, half_t* d) {
        prop16_kernel<<<gP, 256, 0, stream>>>(s, d, offs, csrll, N, 0);
        prop16_kernel<<<gP, 256, 0, stream>>>(s, d, offs, csrll, N, 64);
    };

    // ---- layer 1: hbuf = relu(concat(x,h1,h2,h3) @ W1.T + b1)  (fp16) ----
    prop(x16, t1);
    prop(t1, t2);
    prop(t2, t3);
    gemm16_kernel<true, true><<<gG, 256, 0, stream>>>(x16, t1, t2, t3, w1h, b1, hbuf, nullptr, N);

    // ---- layer 2: out = concat(hbuf,h1,h2,h3) @ W2.T + b2  (fp32 out) ----
    prop(hbuf, t1);
    prop(t1, t2);
    prop(t2, t3);
    gemm16_kernel<false, false><<<gG, 256, 0, stream>>>(hbuf, t1, t2, t3, w2h, b2, nullptr, out, N);
}

// Round 11
// 498.182 us; speedup vs baseline: 1.5289x; 1.5289x over previous
//
#include <hip/hip_runtime.h>
#include <hip/hip_fp16.h>

#define FEAT 128
#define BSH 8              // 256 nodes per bucket
#define BSZ 256
#define NBMAX 400
#define ABLK 4096          // edges per pass-A block
#define CAP 6144           // tmp region capacity per bucket (mean 4092, >30 sigma)

typedef _Float16 half_t;
typedef _Float16 half4 __attribute__((ext_vector_type(4)));
typedef _Float16 half8 __attribute__((ext_vector_type(8)));
typedef float float4v __attribute__((ext_vector_type(4)));

// ---------------- bucket cursor init: fixed regions ----------------
__global__ void binit_kernel(int* __restrict__ gcur, int NB) {
    int b = blockIdx.x * blockDim.x + threadIdx.x;
    if (b < NB) gcur[b * 16] = b * CAP;
}

// ---------------- pass A: LDS-aggregated bucket scatter of raw {r,c} ----------------
__global__ __launch_bounds__(256) void bucketA_kernel(const int* __restrict__ row,
                                                      const int* __restrict__ col,
                                                      int* __restrict__ gcur,
                                                      long long* __restrict__ tmp,
                                                      int E, int NB) {
    __shared__ int hist[NBMAX];
    __shared__ int gbase[NBMAX];
    int t = threadIdx.x;
    int base = blockIdx.x * ABLK;
    for (int i = t; i < NB; i += 256) hist[i] = 0;
    __syncthreads();
    int r[16], c[16];
#pragma unroll
    for (int j = 0; j < 16; ++j) {
        int e = base + j * 256 + t;
        if (e < E) {
            r[j] = __builtin_nontemporal_load(row + e);
            c[j] = __builtin_nontemporal_load(col + e);
            atomicAdd(&hist[c[j] >> BSH], 1);
        } else c[j] = -1;
    }
    __syncthreads();
    for (int b = t; b < NB; b += 256) {
        int cnt = hist[b];
        if (cnt > 0) gbase[b] = atomicAdd(&gcur[b * 16], cnt);
    }
    __syncthreads();
    for (int i = t; i < NB; i += 256) hist[i] = 0;   // reuse as local cursor
    __syncthreads();
#pragma unroll
    for (int j = 0; j < 16; ++j) {
        if (c[j] >= 0) {
            int b = c[j] >> BSH;
            int lpos = atomicAdd(&hist[b], 1);
            long long pk = ((long long)(unsigned)c[j] << 32) | (unsigned)r[j];
            tmp[gbase[b] + lpos] = pk;
        }
    }
}

// ---------------- bucket-count scan ----------------
__global__ __launch_bounds__(512) void bscan_kernel(const int* __restrict__ gcur,
                                                    int* __restrict__ bbase,
                                                    int* __restrict__ offsN, int NB) {
    __shared__ int sd[512];
    int t = threadIdx.x;
    int v = (t < NB) ? (gcur[t * 16] - t * CAP) : 0;
    sd[t] = v;
    __syncthreads();
    for (int o = 1; o < 512; o <<= 1) {
        int u = (t >= o) ? sd[t - o] : 0;
        __syncthreads();
        sd[t] += u;
        __syncthreads();
    }
    if (t < NB) bbase[t] = sd[t] - v;    // exclusive
    if (t == NB - 1) *offsN = sd[t];     // offs[N] = E
}

// ---------------- bdeg: per-bucket degree count (LDS atomics) + offs + dinv ----------------
__global__ __launch_bounds__(256) void bdeg_kernel(const long long* __restrict__ tmp,
                                                   const int* __restrict__ gcur,
                                                   const int* __restrict__ bbase,
                                                   int* __restrict__ offs,
                                                   float* __restrict__ dinv, int N) {
    __shared__ int ldeg[BSZ];
    __shared__ int sums[BSZ];
    int b = blockIdx.x;
    int lo = b << BSH;
    int t = threadIdx.x;
    int cnt = gcur[b * 16] - b * CAP;
    ldeg[t] = 0;
    __syncthreads();
    const long long* reg = tmp + (size_t)b * CAP;
    for (int i = t; i < cnt; i += 256) {
        int c = (int)(__builtin_nontemporal_load(reg + i) >> 32);
        atomicAdd(&ldeg[c - lo], 1);
    }
    __syncthreads();
    int d = ldeg[t];
    sums[t] = d;
    __syncthreads();
    for (int o = 1; o < 256; o <<= 1) {
        int u = (t >= o) ? sums[t - o] : 0;
        __syncthreads();
        sums[t] += u;
        __syncthreads();
    }
    int node = lo + t;
    if (node < N) {
        offs[node] = bbase[b] + sums[t] - d;
        dinv[node] = (d > 0) ? rsqrtf((float)d) : 0.0f;
    }
}

// ---------------- bplace: per-bucket CSR fill with LDS cursors ----------------
__global__ __launch_bounds__(256) void bplace_kernel(const long long* __restrict__ tmp,
                                                     const int* __restrict__ gcur,
                                                     const int* __restrict__ offs,
                                                     const float* __restrict__ dinv,
                                                     int2* __restrict__ csr, int N) {
    __shared__ int lcur[BSZ];
    int b = blockIdx.x;
    int lo = b << BSH;
    int hi = lo + BSZ;
    if (hi > N) hi = N;
    int t = threadIdx.x;
    int cnt = gcur[b * 16] - b * CAP;
    if (t < hi - lo) lcur[t] = offs[lo + t];
    __syncthreads();
    const long long* reg = tmp + (size_t)b * CAP;
    for (int i = t; i < cnt; i += 256) {
        long long pk = __builtin_nontemporal_load(reg + i);
        int r = (int)(pk & 0xffffffffLL);
        int c = (int)(pk >> 32);
        int pos = atomicAdd(&lcur[c - lo], 1);
        float w = dinv[r] * dinv[c];
        int2 o;
        o.x = r;
        o.y = __float_as_int(w);
        csr[pos] = o;
    }
}

// ---------------- fused fp32->fp16 convert for x, W1, W2 ----------------
__global__ void f2h3_kernel(const float* __restrict__ a, half_t* __restrict__ ah, int na4,
                            const float* __restrict__ b, half_t* __restrict__ bh, int nb4,
                            const float* __restrict__ c, half_t* __restrict__ ch, int nc4) {
    int i = blockIdx.x * blockDim.x + threadIdx.x;
    const float* src;
    half_t* dst;
    int j = i;
    if (j < na4) { src = a; dst = ah; }
    else if ((j -= na4) < nb4) { src = b; dst = bh; }
    else if ((j -= nb4) < nc4) { src = c; dst = ch; }
    else return;
    float4 v = ((const float4*)src)[j];
    half4 o;
    o.x = (half_t)v.x; o.y = (half_t)v.y; o.z = (half_t)v.z; o.w = (half_t)v.w;
    ((half4*)dst)[j] = o;
}

// ---------------- fp16 propagation hop: dst[v] = sum_e w_e * src[row_e] ----------------
// One 64-lane wave per node. Lane = (edge-slot q=lane>>4, 16B chunk p=lane&15).
// FOUR independent 1KB gathers in flight (16 edges/iter, 64 lines outstanding/wave).
// OOB slots: pk=0 -> w=0 (harmless hot row-0 read).
__global__ __launch_bounds__(256) void prop16_kernel(const half_t* __restrict__ src,
                                                     half_t* __restrict__ dst,
                                                     const int* __restrict__ offs,
                                                     const long long* __restrict__ csr, int N) {
    int v = blockIdx.x * 4 + (threadIdx.x >> 6);
    if (v >= N) return;
    int lane = threadIdx.x & 63;
    int q = lane >> 4;     // edge slot 0..3
    int p = lane & 15;     // 16B chunk within row
    int s0 = offs[v];
    int s1 = offs[v + 1];
    float acc[8];
#pragma unroll
    for (int j = 0; j < 8; ++j) acc[j] = 0.0f;

    for (int base = s0; base < s1; base += 16) {
        int i0 = base + q;
        int i1 = base + 4 + q;
        int i2 = base + 8 + q;
        int i3 = base + 12 + q;
        long long pk0 = (i0 < s1) ? __builtin_nontemporal_load(csr + i0) : 0LL;
        long long pk1 = (i1 < s1) ? __builtin_nontemporal_load(csr + i1) : 0LL;
        long long pk2 = (i2 < s1) ? __builtin_nontemporal_load(csr + i2) : 0LL;
        long long pk3 = (i3 < s1) ? __builtin_nontemporal_load(csr + i3) : 0LL;
        int r0 = (int)(pk0 & 0xffffffffLL);
        int r1 = (int)(pk1 & 0xffffffffLL);
        int r2 = (int)(pk2 & 0xffffffffLL);
        int r3 = (int)(pk3 & 0xffffffffLL);
        float w0 = __int_as_float((int)(pk0 >> 32));
        float w1 = __int_as_float((int)(pk1 >> 32));
        float w2 = __int_as_float((int)(pk2 >> 32));
        float w3 = __int_as_float((int)(pk3 >> 32));
        half8 va = *(const half8*)(src + (size_t)r0 * FEAT + p * 8);
        half8 vb = *(const half8*)(src + (size_t)r1 * FEAT + p * 8);
        half8 vc = *(const half8*)(src + (size_t)r2 * FEAT + p * 8);
        half8 vd = *(const half8*)(src + (size_t)r3 * FEAT + p * 8);
#pragma unroll
        for (int j = 0; j < 8; ++j) {
            acc[j] = fmaf(w0, (float)va[j], acc[j]);
            acc[j] = fmaf(w1, (float)vb[j], acc[j]);
            acc[j] = fmaf(w2, (float)vc[j], acc[j]);
            acc[j] = fmaf(w3, (float)vd[j], acc[j]);
        }
    }
    // sum the 4 edge slots (lanes p, p+16, p+32, p+48 hold the same features)
#pragma unroll
    for (int j = 0; j < 8; ++j) {
        acc[j] += __shfl_xor(acc[j], 32, 64);
        acc[j] += __shfl_xor(acc[j], 16, 64);
    }
    if (lane < 16) {
        half8 o;
#pragma unroll
        for (int j = 0; j < 8; ++j) o[j] = (half_t)acc[j];
        *(half8*)(dst + (size_t)v * FEAT + p * 8) = o;
    }
}

// ---------------- MFMA GEMM: out[M,128] = concat(H0..H3)[M,512] @ W[128,512].T + b ----------------
template <bool RELU, bool HALFOUT>
__global__ __launch_bounds__(256) void gemm16_kernel(const half_t* __restrict__ H0,
                                                     const half_t* __restrict__ H1,
                                                     const half_t* __restrict__ H2,
                                                     const half_t* __restrict__ H3,
                                                     const half_t* __restrict__ W,   // [128][512] fp16
                                                     const float* __restrict__ bias, // [128] fp32
                                                     half_t* __restrict__ out_h,
                                                     float* __restrict__ out_f, int N) {
    __shared__ half_t ws[128][40];   // [o][k-slice 32, pad->40]
    const int tid = threadIdx.x;
    const int lane = tid & 63;
    const int wid = tid >> 6;
    const int lr = lane & 15;        // m-in-tile
    const int lk = lane >> 4;        // 0..3
    const int m = blockIdx.x * 64 + wid * 16 + lr;
    const bool mok = (m < N);

    float4v acc[8];
#pragma unroll
    for (int ct = 0; ct < 8; ++ct) acc[ct] = (float4v)0.0f;

    const half_t* Hs[4] = {H0, H1, H2, H3};
    const int wo = tid >> 1;
    const int wh = tid & 1;

#pragma unroll
    for (int b = 0; b < 4; ++b) {
        const half_t* __restrict__ H = Hs[b];
#pragma unroll
        for (int kt = 0; kt < 128; kt += 32) {
            half8 hfrag = (half8)(half_t)0.0f;
            if (mok) hfrag = *(const half8*)(H + (size_t)m * FEAT + kt + lk * 8);
            const half8* wsrc = (const half8*)(W + (size_t)wo * 512 + b * 128 + kt + wh * 16);
            half8 w0 = wsrc[0];
            half8 w1 = wsrc[1];
            __syncthreads();
            *(half8*)&ws[wo][wh * 16 + 0] = w0;
            *(half8*)&ws[wo][wh * 16 + 8] = w1;
            __syncthreads();
#pragma unroll
            for (int ct = 0; ct < 8; ++ct) {
                half8 wfrag = *(const half8*)&ws[ct * 16 + lr][lk * 8];
                acc[ct] = __builtin_amdgcn_mfma_f32_16x16x32_f16(wfrag, hfrag, acc[ct], 0, 0, 0);
            }
        }
    }

    if (mok) {
#pragma unroll
        for (int ct = 0; ct < 8; ++ct) {
            int o = ct * 16 + lk * 4;
            float4 bv = *(const float4*)(bias + o);
            float r0 = acc[ct][0] + bv.x;
            float r1 = acc[ct][1] + bv.y;
            float r2 = acc[ct][2] + bv.z;
            float r3 = acc[ct][3] + bv.w;
            if (RELU) {
                r0 = fmaxf(r0, 0.0f); r1 = fmaxf(r1, 0.0f);
                r2 = fmaxf(r2, 0.0f); r3 = fmaxf(r3, 0.0f);
            }
            if (HALFOUT) {
                half4 hv;
                hv.x = (half_t)r0; hv.y = (half_t)r1; hv.z = (half_t)r2; hv.w = (half_t)r3;
                *(half4*)(out_h + (size_t)m * FEAT + o) = hv;
            } else {
                float4 fv;
                fv.x = r0; fv.y = r1; fv.z = r2; fv.w = r3;
                *(float4*)(out_f + (size_t)m * FEAT + o) = fv;
            }
        }
    }
}

extern "C" void kernel_launch(void* const* d_in, const int* in_sizes, int n_in,
                              void* d_out, int out_size, void* d_ws, size_t ws_size,
                              hipStream_t stream) {
    const float* x   = (const float*)d_in[0];
    const int*   ei  = (const int*)d_in[1];
    const float* W1  = (const float*)d_in[2];
    const float* b1  = (const float*)d_in[3];
    const float* W2  = (const float*)d_in[4];
    const float* b2  = (const float*)d_in[5];
    float* out = (float*)d_out;

    const int N = in_sizes[0] / FEAT;       // 100000
    const int E = in_sizes[1] / 2;          // 1600000
    const int* row = ei;
    const int* col = ei + E;
    const int NB = (N + BSZ - 1) / BSZ;     // buckets (391)

    // workspace carve
    size_t off = 0;
    auto carve = [&](size_t bytes) -> void* {
        void* p = (char*)d_ws + off;
        off += (bytes + 255) & ~(size_t)255;
        return p;
    };
    float*     dinv = (float*)carve((size_t)N * 4);
    int*       offs = (int*)carve((size_t)(N + 1) * 4);
    int*       bbase = (int*)carve((size_t)NB * 4);
    int*       gcur = (int*)carve((size_t)NB * 16 * 4);   // padded cursors
    long long* tmp  = (long long*)carve((size_t)NB * CAP * 8);
    int2*      csr  = (int2*)carve((size_t)E * 8);
    half_t*    x16  = (half_t*)carve((size_t)N * FEAT * 2);
    half_t*    t1   = (half_t*)carve((size_t)N * FEAT * 2);
    half_t*    t2   = (half_t*)carve((size_t)N * FEAT * 2);
    half_t*    t3   = (half_t*)carve((size_t)N * FEAT * 2);
    half_t*    hbuf = (half_t*)carve((size_t)N * FEAT * 2);
    half_t*    w1h  = (half_t*)carve((size_t)FEAT * 512 * 2);
    half_t*    w2h  = (half_t*)carve((size_t)FEAT * 512 * 2);

    const int tB = 256;
    const int gA = (E + ABLK - 1) / ABLK;       // pass-A blocks
    const int gP = (N + 3) / 4;                 // prop16 blocks (4 nodes/block, 1 wave/node)
    const int gG = (N + 63) / 64;               // gemm16 blocks (64 rows/block)
    const int xt4 = N * FEAT / 4;
    const int wt4 = FEAT * 512 / 4;
    const int cvt_total = xt4 + 2 * wt4;

    // ---- CSR build: bucket scatter -> bucket scan -> LDS degree count -> place ----
    binit_kernel<<<(NB + tB - 1) / tB, tB, 0, stream>>>(gcur, NB);
    bucketA_kernel<<<gA, 256, 0, stream>>>(row, col, gcur, tmp, E, NB);
    bscan_kernel<<<1, 512, 0, stream>>>(gcur, bbase, offs + N, NB);
    bdeg_kernel<<<NB, 256, 0, stream>>>(tmp, gcur, bbase, offs, dinv, N);
    bplace_kernel<<<NB, 256, 0, stream>>>(tmp, gcur, offs, dinv, csr, N);

    // ---- fp16 conversions (fused) ----
    f2h3_kernel<<<(cvt_total + tB - 1) / tB, tB, 0, stream>>>(x, x16, xt4, W1, w1h, wt4, W2, w2h, wt4);

    const long long* csrll = (const long long*)csr;

    // ---- layer 1: hbuf = relu(concat(x,h1,h2,h3) @ W1.T + b1)  (fp16) ----
    prop16_kernel<<<gP, 256, 0, stream>>>(x16, t1, offs, csrll, N);
    prop16_kernel<<<gP, 256, 0, stream>>>(t1, t2, offs, csrll, N);
    prop16_kernel<<<gP, 256, 0, stream>>>(t2, t3, offs, csrll, N);
    gemm16_kernel<true, true><<<gG, 256, 0, stream>>>(x16, t1, t2, t3, w1h, b1, hbuf, nullptr, N);

    // ---- layer 2: out = concat(hbuf,h1,h2,h3) @ W2.T + b2  (fp32 out) ----
    prop16_kernel<<<gP, 256, 0, stream>>>(hbuf, t1, offs, csrll, N);
    prop16_kernel<<<gP, 256, 0, stream>>>(t1, t2, offs, csrll, N);
    prop16_kernel<<<gP, 256, 0, stream>>>(t2, t3, offs, csrll, N);
    gemm16_kernel<false, false><<<gG, 256, 0, stream>>>(hbuf, t1, t2, t3, w2h, b2, nullptr, out, N);
}